// Round 16
// baseline (790.949 us; speedup 1.0000x reference)
//
#include <hip/hip_runtime.h>
#include <hip/hip_bf16.h>

// ---------------------------------------------------------------------------
// DeepSeek decoder layer. f32 inputs/outputs; internal bf16 (+f32 residual).
// r16 = r15 + (1) cvtw+addnorm1 merged into one prep_k launch;
//            + (2) DIAGNOSTIC: 20 empty nop_k launches appended after the
//              final kernel -> (dur - 754)/20 = per-launch overhead G.
// ---------------------------------------------------------------------------

typedef __attribute__((ext_vector_type(4))) float  f32x4;
typedef __attribute__((ext_vector_type(8))) short  short8;
typedef __attribute__((ext_vector_type(8))) unsigned short ushort8;

#define SS    512
#define DD    2048
#define NH    16
#define HDIM  128
#define NQKV  6144
#define NEXP  64
#define TOPK  6
#define IEXP  1408
#define ISHE  2816
#define NT0   128
#define NT1   120
#define ATT_SCALE 0.08838834764831845f

__device__ __forceinline__ float u2f(unsigned short u) {
  return __uint_as_float(((unsigned int)u) << 16);
}
__device__ __forceinline__ unsigned short f2u(float f) {
  __hip_bfloat16 h = __float2bfloat16(f);   // RNE
  return *reinterpret_cast<unsigned short*>(&h);
}
__device__ __forceinline__ ushort8 cvt8(f32x4 a, f32x4 b) {
  ushort8 r;
  r[0]=f2u(a[0]); r[1]=f2u(a[1]); r[2]=f2u(a[2]); r[3]=f2u(a[3]);
  r[4]=f2u(b[0]); r[5]=f2u(b[1]); r[6]=f2u(b[2]); r[7]=f2u(b[3]);
  return r;
}

typedef __attribute__((address_space(3))) unsigned int lds_uint;
typedef const __attribute__((address_space(1))) unsigned int ga_uint;
__device__ __forceinline__ void gll16(const void* g, void* l) {
  __builtin_amdgcn_global_load_lds((ga_uint*)g, (lds_uint*)l, 16, 0, 0);
}

// --------- empty probe kernel (per-launch overhead measurement) -------------
__global__ void nop_k() {}

// ------ prep: blocks [0,SS) = addnorm1; blocks [SS,..) = weight cvt ---------
__global__ __launch_bounds__(256) void prep_k(
    const float* __restrict__ hid, const float* __restrict__ res,
    const float* __restrict__ w, float* __restrict__ x1,
    unsigned short* __restrict__ h1,
    const float* __restrict__ wqkv, const float* __restrict__ wo,
    const float* __restrict__ sw1, const float* __restrict__ sw2,
    unsigned short* __restrict__ wqkv_bf, unsigned short* __restrict__ wo_bf,
    unsigned short* __restrict__ sw1_bf, unsigned short* __restrict__ sw2_bf)
{
  int b = blockIdx.x, tid = threadIdx.x;
  if (b < SS) {
    long long base = (long long)b * DD + tid * 8;
    float x[8]; float ss = 0.f;
#pragma unroll
    for (int i = 0; i < 8; i++) {
      x[i] = hid[base + i] + res[base + i];
      ss += x[i] * x[i]; x1[base + i] = x[i];
    }
#pragma unroll
    for (int o = 1; o < 64; o <<= 1) ss += __shfl_xor(ss, o);
    __shared__ float r4[4];
    if ((tid & 63) == 0) r4[tid >> 6] = ss;
    __syncthreads();
    ss = r4[0] + r4[1] + r4[2] + r4[3];
    float rr = rsqrtf(ss * (1.f / DD) + 1e-6f);
#pragma unroll
    for (int i = 0; i < 8; i++) h1[base + i] = f2u(x[i] * rr * w[tid * 8 + i]);
    return;
  }
  long long i = ((long long)(b - SS) * 256 + tid) * 8;
  const long long S1 = (long long)NQKV * DD;
  const long long S2 = S1 + (long long)DD * DD;
  const long long S3 = S2 + (long long)2 * ISHE * DD;
  const float* src; unsigned short* dst; long long j;
  if (i < S1)      { src = wqkv; dst = wqkv_bf; j = i; }
  else if (i < S2) { src = wo;   dst = wo_bf;   j = i - S1; }
  else if (i < S3) { src = sw1;  dst = sw1_bf;  j = i - S2; }
  else             { src = sw2;  dst = sw2_bf;  j = i - S3; }
  f32x4 a = *(const f32x4*)(src + j);
  f32x4 bb = *(const f32x4*)(src + j + 4);
  *(ushort8*)(dst + j) = cvt8(a, bb);
}

// ------ FUSED addnorm2 + gating: 64 blocks x 8 tokens; h3 parked in LDS -----
__global__ __launch_bounds__(256) void an2gate_k(
    const unsigned short* __restrict__ attn, const float* __restrict__ x1,
    const float* __restrict__ w, float* __restrict__ resid_out,
    unsigned short* __restrict__ h3, const float* __restrict__ gw,
    int* __restrict__ topi, float* __restrict__ topw)
{
  __shared__ unsigned short hs[8][DD];
  __shared__ float r4[4];
  __shared__ float p[8][NEXP];
  int b = blockIdx.x, tid = threadIdx.x;

  for (int tk = 0; tk < 8; tk++) {
    int t = b * 8 + tk;
    long long base = (long long)t * DD + tid * 8;
    ushort8 va = *(const ushort8*)(attn + base);
    float x[8]; float ss = 0.f;
#pragma unroll
    for (int i = 0; i < 8; i++) {
      x[i] = u2f(va[i]) + x1[base + i]; ss += x[i] * x[i];
      resid_out[base + i] = x[i];
    }
#pragma unroll
    for (int o = 1; o < 64; o <<= 1) ss += __shfl_xor(ss, o);
    if ((tid & 63) == 0) r4[tid >> 6] = ss;
    __syncthreads();
    ss = r4[0] + r4[1] + r4[2] + r4[3];
    float rr = rsqrtf(ss * (1.f / DD) + 1e-6f);
    ushort8 hv;
#pragma unroll
    for (int i = 0; i < 8; i++) hv[i] = f2u(x[i] * rr * w[tid * 8 + i]);
    *(ushort8*)&hs[tk][tid * 8] = hv;
    *(ushort8*)(h3 + base) = hv;
    __syncthreads();
  }

  int e = tid & 63, g = tid >> 6;
  const float* wr = gw + (long long)e * DD;
  const unsigned short* h0 = hs[g * 2];
  const unsigned short* h1r = hs[g * 2 + 1];
  float a0 = 0.f, a1 = 0.f;
  for (int k = 0; k < DD; k += 8) {
    f32x4 w0 = *(const f32x4*)(wr + k);
    f32x4 w1 = *(const f32x4*)(wr + k + 4);
    ushort8 x0 = *(const ushort8*)(h0 + k);
    ushort8 x1v = *(const ushort8*)(h1r + k);
    a0 += u2f(x0[0])*w0[0] + u2f(x0[1])*w0[1] + u2f(x0[2])*w0[2] + u2f(x0[3])*w0[3]
        + u2f(x0[4])*w1[0] + u2f(x0[5])*w1[1] + u2f(x0[6])*w1[2] + u2f(x0[7])*w1[3];
    a1 += u2f(x1v[0])*w0[0] + u2f(x1v[1])*w0[1] + u2f(x1v[2])*w0[2] + u2f(x1v[3])*w0[3]
        + u2f(x1v[4])*w1[0] + u2f(x1v[5])*w1[1] + u2f(x1v[6])*w1[2] + u2f(x1v[7])*w1[3];
  }
  p[g * 2][e] = a0; p[g * 2 + 1][e] = a1;
  __syncthreads();
  if (tid < 8) {
    int t = b * 8 + tid;
    float* pr = p[tid];
    float mx = -1e30f;
    for (int j = 0; j < NEXP; j++) mx = fmaxf(mx, pr[j]);
    float s = 0.f;
    for (int j = 0; j < NEXP; j++) { pr[j] = __expf(pr[j] - mx); s += pr[j]; }
    float invs = 1.f / s;
    for (int j = 0; j < NEXP; j++) pr[j] *= invs;
    for (int r = 0; r < TOPK; r++) {
      int bi = 0; float bv = -1.f;
      for (int j = 0; j < NEXP; j++) if (pr[j] > bv) { bv = pr[j]; bi = j; }
      topi[t * TOPK + r] = bi; topw[t * TOPK + r] = bv; pr[bi] = -2.f;
    }
  }
}

// ---------------------------------------------------------------------------
// Dense bf16 x bf16 GEMM via global_load_lds, double-buffered (r11 engine).
// ---------------------------------------------------------------------------
__global__ __launch_bounds__(256) void gemm_bb(
    const unsigned short* __restrict__ A, const unsigned short* __restrict__ W,
    unsigned short* __restrict__ C, int Nh, int K, int lda)
{
  __shared__ __align__(16) unsigned short As[2][64][64];
  __shared__ __align__(16) unsigned short Bs[2][64][64];

  int m0 = blockIdx.y * 64;
  int n0 = blockIdx.x * 64;
  int tid = threadIdx.x, lane = tid & 63, w = tid >> 6;

  const unsigned short* asrc[2];
  const unsigned short* bsrc[2];
#pragma unroll
  for (int i = 0; i < 2; i++) {
    int c = w + i * 4;
    int r = c * 8 + (lane >> 3);
    int col = ((lane & 7) ^ (lane >> 3)) << 3;
    asrc[i] = A + (long long)(m0 + r) * lda + col;
    bsrc[i] = W + (long long)(n0 + r) * K + col;
  }

  int wm = (w >> 1) * 32, wn = (w & 1) * 32;
  int l15 = lane & 15, hi = lane >> 4;
  int key = l15 & 7;

  f32x4 acc[2][2] = {};

#define BSTAGE(buf, k0)                                                  \
  do {                                                                   \
    gll16((const char*)asrc[0] + (k0) * 2, &As[buf][w * 8][0]);          \
    gll16((const char*)asrc[1] + (k0) * 2, &As[buf][(w + 4) * 8][0]);    \
    gll16((const char*)bsrc[0] + (k0) * 2, &Bs[buf][w * 8][0]);          \
    gll16((const char*)bsrc[1] + (k0) * 2, &Bs[buf][(w + 4) * 8][0]);    \
  } while (0)

  BSTAGE(0, 0);
  int buf = 0;
  for (int k0 = 0; k0 < K; k0 += 64, buf ^= 1) {
    __syncthreads();
    if (k0 + 64 < K) BSTAGE(buf ^ 1, k0 + 64);
#pragma unroll
    for (int kk = 0; kk < 2; kk++) {
      short8 fa[2], fb[2];
#pragma unroll
      for (int f = 0; f < 2; f++) {
        fa[f] = *(const short8*)&As[buf][wm + f * 16 + l15][(((kk << 2) + hi) ^ key) << 3];
        fb[f] = *(const short8*)&Bs[buf][wn + f * 16 + l15][(((kk << 2) + hi) ^ key) << 3];
      }
#pragma unroll
      for (int fm = 0; fm < 2; fm++)
#pragma unroll
        for (int fn = 0; fn < 2; fn++)
          acc[fm][fn] = __builtin_amdgcn_mfma_f32_16x16x32_bf16(fa[fm], fb[fn], acc[fm][fn], 0, 0, 0);
    }
  }
#undef BSTAGE

  int r0q = hi * 4;
#pragma unroll
  for (int fm = 0; fm < 2; fm++) {
#pragma unroll
    for (int j = 0; j < 4; j++) {
      int m = m0 + wm + fm * 16 + r0q + j;
      unsigned short* Cp = C + (long long)m * Nh + n0 + wn;
#pragma unroll
      for (int fn = 0; fn < 2; fn++)
        Cp[fn * 16 + l15] = f2u(acc[fm][fn][j]);
    }
  }
}

// ---------------------------------------------------------------------------
// MoE GEMM: experts (f32 W) + shared expert (bf16 W, e==NEXP).
// ---------------------------------------------------------------------------
template<int STAGE>
__global__ __launch_bounds__(256) void moe_k(
    const unsigned short* __restrict__ h3,
    const unsigned short* __restrict__ act_e_in, const unsigned short* __restrict__ act_sh_in,
    const float* __restrict__ w1, const unsigned short* __restrict__ sw1_bf,
    const float* __restrict__ w2, const unsigned short* __restrict__ sw2_bf,
    unsigned short* __restrict__ act_e_out, unsigned short* __restrict__ act_sh_out,
    unsigned short* __restrict__ out_e, unsigned short* __restrict__ shared_o,
    const int* __restrict__ e_cnt, const int* __restrict__ e_off,
    const int* __restrict__ tok_list, const float* __restrict__ wslot,
    const int* __restrict__ tile_tab, const int* __restrict__ ntiles)
{
  constexpr bool SILU = (STAGE == 0);
  __shared__ __align__(16) unsigned short As[64][72];
  __shared__ __align__(16) unsigned short Bg[64][72];
  __shared__ __align__(16) unsigned short Bu[SILU ? 64 : 1][72];

  int yr = blockIdx.y;
  int y;
  if (STAGE == 0) y = (yr < 16) ? yr : 16 + ((yr - 16) & 7) * 14 + ((yr - 16) >> 3);
  else            y = (yr < 8)  ? yr : 8  + ((yr - 8) & 7) * 14 + ((yr - 8) >> 3);
  if (y >= *ntiles) return;
  int tt = tile_tab[y];
  int e = tt >> 16;
  int half = (tt >> 8) & 1;
  int m0 = (tt & 255) * 64;
  bool sh = (e == NEXP);
  int cnt  = sh ? SS : e_cnt[e];
  int roff = sh ? 0 : e_off[e];
  int n0 = blockIdx.x * 64 + ((STAGE == 0 && sh) ? half * IEXP : 0);

  int Nh, K, lda;
  const float* Wb32 = nullptr;
  const unsigned short* Wb16 = nullptr;
  const unsigned short* Abase;
  unsigned short* Cb;
  if (STAGE == 0) {
    K = DD; lda = DD; Abase = h3;
    if (sh) { Nh = ISHE; Wb16 = sw1_bf; Cb = act_sh_out; }
    else    { Nh = IEXP; Wb32 = w1 + (long long)e * 2 * IEXP * DD; Cb = act_e_out; }
  } else {
    Nh = DD;
    if (sh) { K = ISHE; lda = ISHE; Abase = act_sh_in; Wb16 = sw2_bf; Cb = shared_o; }
    else    { K = IEXP; lda = IEXP; Abase = act_e_in;
              Wb32 = w2 + (long long)e * DD * IEXP; Cb = out_e; }
  }

  int tid = threadIdx.x;
  int sr  = tid >> 2;
  int sce = (tid & 3) * 16;

  int am = m0 + sr; if (am >= cnt) am = cnt - 1;
  int arow;
  if (STAGE == 0) arow = sh ? am : tok_list[roff + am];
  else            arow = sh ? am : roff + am;
  const unsigned short* ap = Abase + (long long)arow * lda + sce;
  const float*          gp32 = Wb32 ? (Wb32 + (long long)(n0 + sr) * K + sce) : nullptr;
  const float*          up32 = (Wb32 && SILU) ? (Wb32 + (long long)(Nh + n0 + sr) * K + sce) : nullptr;
  const unsigned short* gp16 = Wb16 ? (Wb16 + (long long)(n0 + sr) * K + sce) : nullptr;
  const unsigned short* up16 = (Wb16 && SILU) ? (Wb16 + (long long)(Nh + n0 + sr) * K + sce) : nullptr;

  int lane = tid & 63, wid = tid >> 6;
  int wm = (wid >> 1) * 32, wn = (wid & 1) * 32;
  int l15 = lane & 15, hi = lane >> 4;

  f32x4 acc[2][2] = {};
  f32x4 accU[2][2] = {};
  ushort8 raA0, raA1, raB0, raB1;
  f32x4 rgA[4], ruA[4], rgB[4], ruB[4];
  union BC { f32x4 f; ushort8 s; };

#define MLOAD(k, r0, r1, g, u)                                     \
  do {                                                             \
    r0 = *(const ushort8*)(ap + (k));                              \
    r1 = *(const ushort8*)(ap + (k) + 8);                          \
    if (sh) {                                                      \
      g[0] = *(const f32x4*)(gp16 + (k));                          \
      g[1] = *(const f32x4*)(gp16 + (k) + 8);                      \
      if (SILU) {                                                  \
        u[0] = *(const f32x4*)(up16 + (k));                        \
        u[1] = *(const f32x4*)(up16 + (k) + 8);                    \
      }                                                            \
    } else {                                                       \
      _Pragma("unroll")                                            \
      for (int i_ = 0; i_ < 4; i_++) g[i_] = *(const f32x4*)(gp32 + (k) + 4 * i_); \
      if (SILU) {                                                  \
        _Pragma("unroll")                                          \
        for (int i_ = 0; i_ < 4; i_++) u[i_] = *(const f32x4*)(up32 + (k) + 4 * i_); \
      }                                                            \
    }                                                              \
  } while (0)

#define MSTORE(r0, r1, g, u)                                       \
  do {                                                             \
    *(ushort8*)&As[sr][sce]     = r0;                              \
    *(ushort8*)&As[sr][sce + 8] = r1;                              \
    if (sh) {                                                      \
      BC b0, b1; b0.f = g[0]; b1.f = g[1];                         \
      *(ushort8*)&Bg[sr][sce]     = b0.s;                          \
      *(ushort8*)&Bg[sr][sce + 8] = b1.s;                          \
      if (SILU) {                                                  \
        BC c0, c1; c0.f = u[0]; c1.f = u[1];                       \
        *(ushort8*)&Bu[sr][sce]     = c0.s;                        \
        *(ushort8*)&Bu[sr][sce + 8] = c1.s;                        \
      }                                                            \
    } else {                                                       \
      *(ushort8*)&Bg[sr][sce]     = cvt8(g[0], g[1]);              \
      *(ushort8*)&Bg[sr][sce + 8] = cvt8(g[2], g[3]);              \
      if (SILU) {                                                  \
        *(ushort8*)&Bu[sr][sce]     = cvt8(u[0], u[1]);            \
        *(ushort8*)&Bu[sr][sce + 8] = cvt8(u[2], u[3]);            \
      }                                                            \
    }                                                              \
  } while (0)

#define MMFMA                                                      \
  do {                                                             \
    _Pragma("unroll")                                              \
    for (int kk = 0; kk < 2; kk++) {                               \
      int kc = kk * 32 + hi * 8;                                   \
      short8 fa[2], fg[2];                                         \
      _Pragma("unroll")                                            \
      for (int f = 0; f < 2; f++) {                                \
        fa[f] = *(const short8*)&As[wm + f * 16 + l15][kc];        \
        fg[f] = *(const short8*)&Bg[wn + f * 16 + l15][kc];        \
      }                                                            \
      _Pragma("unroll")                                            \
      for (int fm = 0; fm < 2; fm++)                               \
        _Pragma("unroll")                                          \
        for (int fn = 0; fn < 2; fn++)                             \
          acc[fm][fn] = __builtin_amdgcn_mfma_f32_16x16x32_bf16(fa[fm], fg[fn], acc[fm][fn], 0, 0, 0); \
      if (SILU) {                                                  \
        short8 fu[2];                                              \
        _Pragma("unroll")                                          \
        for (int f = 0; f < 2; f++) fu[f] = *(const short8*)&Bu[wn + f * 16 + l15][kc]; \
        _Pragma("unroll")                                          \
        for (int fm = 0; fm < 2; fm++)                             \
          _Pragma("unroll")                                        \
          for (int fn = 0; fn < 2; fn++)                           \
            accU[fm][fn] = __builtin_amdgcn_mfma_f32_16x16x32_bf16(fa[fm], fu[fn], accU[fm][fn], 0, 0, 0); \
      }                                                            \
    }                                                              \
  } while (0)

  MLOAD(0,  raA0, raA1, rgA, ruA);
  MLOAD(64, raB0, raB1, rgB, ruB);
  for (int k0 = 0; k0 < K; k0 += 128) {
    __syncthreads();
    MSTORE(raA0, raA1, rgA, ruA);
    __syncthreads();
    if (k0 + 128 < K) MLOAD(k0 + 128, raA0, raA1, rgA, ruA);
    MMFMA;
    __syncthreads();
    MSTORE(raB0, raB1, rgB, ruB);
    __syncthreads();
    if (k0 + 192 < K) MLOAD(k0 + 192, raB0, raB1, rgB, ruB);
    MMFMA;
  }
#undef MLOAD
#undef MSTORE
#undef MMFMA

  int r0q = hi * 4;
#pragma unroll
  for (int fm = 0; fm < 2; fm++) {
#pragma unroll
    for (int j = 0; j < 4; j++) {
      int m = m0 + wm + fm * 16 + r0q + j;
      if (m >= cnt) continue;
      long long crow = sh ? m : (roff + m);
      float scale = (STAGE == 1 && !sh) ? wslot[crow] : 1.f;
      unsigned short* Cp = Cb + crow * (long long)Nh + n0 + wn;
#pragma unroll
      for (int fn = 0; fn < 2; fn++) {
        float v;
        if (SILU) {
          float g = acc[fm][fn][j], u = accU[fm][fn][j];
          v = (g / (1.f + __expf(-g))) * u;
        } else v = acc[fm][fn][j];
        Cp[fn * 16 + l15] = f2u(v * scale);
      }
    }
  }
}

// ------------------------------ RoPE (neox) --------------------------------
__global__ __launch_bounds__(256) void rope_k(
    const int* __restrict__ pos, const unsigned short* __restrict__ qkv,
    unsigned short* __restrict__ qr, unsigned short* __restrict__ kr)
{
  int t = blockIdx.x, tid = threadIdx.x;
  __shared__ float cs[64], sn[64];
  if (tid < 64) {
    float inv = __expf(-((float)(2 * tid) / 128.f) * logf(10000.f));
    float ang = (float)pos[t] * inv;
    cs[tid] = cosf(ang); sn[tid] = sinf(ang);
  }
  __syncthreads();
  const unsigned short* row = qkv + (long long)t * NQKV;
  for (int idx = tid; idx < NH * 64; idx += 256) {
    int hh = idx >> 6, i = idx & 63;
    long long o = ((long long)hh * SS + t) * HDIM;
    float x1 = u2f(row[hh*128 + i]), x2 = u2f(row[hh*128 + i + 64]);
    qr[o + i]      = f2u(x1 * cs[i] - x2 * sn[i]);
    qr[o + i + 64] = f2u(x2 * cs[i] + x1 * sn[i]);
    float y1 = u2f(row[2048 + hh*128 + i]), y2 = u2f(row[2048 + hh*128 + i + 64]);
    kr[o + i]      = f2u(y1 * cs[i] - y2 * sn[i]);
    kr[o + i + 64] = f2u(y2 * cs[i] + y1 * sn[i]);
  }
}

// ------- MFMA flash attention, 32 q-rows / block, 2 waves, 256 blocks -------
__global__ __launch_bounds__(128) void attn_k(
    const unsigned short* __restrict__ qr, const unsigned short* __restrict__ kr,
    const unsigned short* __restrict__ qkv, unsigned short* __restrict__ ctx)
{
  int h = blockIdx.x, qt = blockIdx.y, q0 = qt * 32;
  int tid = threadIdx.x, lane = tid & 63, w = tid >> 6;
  int l15 = lane & 15, hi = lane >> 4;

  __shared__ unsigned short Vt[128][72];
  __shared__ unsigned short Pl[2][16][72];

  short8 qf[4];
  const unsigned short* Qb = qr + ((long long)h * SS + q0 + w * 16 + l15) * HDIM + hi * 8;
#pragma unroll
  for (int kf = 0; kf < 4; kf++) qf[kf] = *(const short8*)(Qb + kf * 32);

  f32x4 o[8] = {};
  float m_run[4] = {-1e30f, -1e30f, -1e30f, -1e30f};
  float l_run[4] = {};
  int myq = w * 16 + hi * 4;

  int T = (q0 + 31) >> 6;
  int qoff = q0 - 64 * T;
  for (int kt = 0; kt <= T; kt++) {
    int kbase = kt * 64;
    __syncthreads();
    {
      int r = lane, d0 = w * 64;
      const unsigned short* Vp = qkv + (long long)(kbase + r) * NQKV + 4096 + h * HDIM + d0;
#pragma unroll
      for (int c = 0; c < 8; c++) {
        ushort8 v = *(const ushort8*)(Vp + c * 8);
#pragma unroll
        for (int i = 0; i < 8; i++) Vt[d0 + c * 8 + i][r] = v[i];
      }
    }
    f32x4 s[4] = {};
    const unsigned short* Kb = kr + ((long long)h * SS + kbase) * HDIM + hi * 8;
#pragma unroll
    for (int nf = 0; nf < 4; nf++) {
      const unsigned short* Kp = Kb + (long long)(nf * 16 + l15) * HDIM;
#pragma unroll
      for (int kf = 0; kf < 4; kf++) {
        short8 kf8 = *(const short8*)(Kp + kf * 32);
        s[nf] = __builtin_amdgcn_mfma_f32_16x16x32_bf16(qf[kf], kf8, s[nf], 0, 0, 0);
      }
    }
    bool last = (kt == T);
#pragma unroll
    for (int nf = 0; nf < 4; nf++) {
      int keyl = nf * 16 + l15;
#pragma unroll
      for (int j = 0; j < 4; j++) {
        float sv = s[nf][j] * ATT_SCALE;
        if (last && keyl > qoff + myq + j) sv = -1e30f;
        s[nf][j] = sv;
      }
    }
    float corr[4], mnew[4];
#pragma unroll
    for (int j = 0; j < 4; j++) {
      float mv = fmaxf(fmaxf(s[0][j], s[1][j]), fmaxf(s[2][j], s[3][j]));
#pragma unroll
      for (int ox = 1; ox < 16; ox <<= 1) mv = fmaxf(mv, __shfl_xor(mv, ox));
      mnew[j] = fmaxf(m_run[j], mv);
      corr[j] = __expf(m_run[j] - mnew[j]);
      m_run[j] = mnew[j];
    }
#pragma unroll
    for (int nf8 = 0; nf8 < 8; nf8++)
#pragma unroll
      for (int j = 0; j < 4; j++) o[nf8][j] *= corr[j];
    float rs[4] = {};
#pragma unroll
    for (int nf = 0; nf < 4; nf++) {
#pragma unroll
      for (int j = 0; j < 4; j++) {
        float pv = __expf(s[nf][j] - mnew[j]);
        rs[j] += pv;
        Pl[w][hi * 4 + j][nf * 16 + l15] = f2u(pv);
      }
    }
#pragma unroll
    for (int j = 0; j < 4; j++) {
      float sv = rs[j];
#pragma unroll
      for (int ox = 1; ox < 16; ox <<= 1) sv += __shfl_xor(sv, ox);
      l_run[j] = l_run[j] * corr[j] + sv;
    }
    __syncthreads();
#pragma unroll
    for (int kf2 = 0; kf2 < 2; kf2++) {
      short8 pa = *(const short8*)&Pl[w][l15][kf2 * 32 + hi * 8];
#pragma unroll
      for (int nf8 = 0; nf8 < 8; nf8++) {
        short8 vb = *(const short8*)&Vt[nf8 * 16 + l15][kf2 * 32 + hi * 8];
        o[nf8] = __builtin_amdgcn_mfma_f32_16x16x32_bf16(pa, vb, o[nf8], 0, 0, 0);
      }
    }
  }
#pragma unroll
  for (int j = 0; j < 4; j++) {
    float inv = 1.f / l_run[j];
    long long t = q0 + myq + j;
    unsigned short* Cp = ctx + t * (long long)DD + h * HDIM;
#pragma unroll
    for (int nf8 = 0; nf8 < 8; nf8++)
      Cp[nf8 * 16 + l15] = f2u(o[nf8][j] * inv);
  }
}

// --------------- routing: quartered scans; builds both tile tables ----------
__global__ __launch_bounds__(256) void route_k(
    const int* __restrict__ topi, const float* __restrict__ topw,
    int* __restrict__ ecnt, int* __restrict__ eoff,
    int* __restrict__ tok_list, int* __restrict__ slotg,
    float* __restrict__ wslot, int* __restrict__ tile_tab0,
    int* __restrict__ tile_tab1, int* __restrict__ ntiles0,
    int* __restrict__ ntiles1)
{
  __shared__ int ti[SS * TOPK];
  __shared__ int c4[NEXP][4];
  __shared__ int ctot[NEXP];
  __shared__ int offs[NEXP + 1];
  int tid = threadIdx.x;
  for (int i = tid; i < SS * TOPK; i += 256) ti[i] = topi[i];
  __syncthreads();
  int e = tid >> 2, q = tid & 3;
  const int QW = SS * TOPK / 4;
  int lo = q * QW, hiQ = lo + QW;
  int n = 0;
  for (int i = lo; i < hiQ; i++) n += (ti[i] == e);
  c4[e][q] = n;
  __syncthreads();
  if (q == 0) {
    int s = c4[e][0] + c4[e][1] + c4[e][2] + c4[e][3];
    ctot[e] = s; ecnt[e] = s;
  }
  __syncthreads();
  if (tid == 0) {
    offs[0] = 0;
    for (int k = 0; k < NEXP; k++) offs[k + 1] = offs[k] + ctot[k];
    int n0 = 0, n1 = 0;
    for (int mt = 0; mt < SS / 64; mt++) {
      tile_tab0[n0++] = (NEXP << 16) | (0 << 8) | mt;
      tile_tab0[n0++] = (NEXP << 16) | (1 << 8) | mt;
      tile_tab1[n1++] = (NEXP << 16) | mt;
    }
    for (int k = 0; k < NEXP; k++)
      for (int mt = 0; mt * 64 < ctot[k]; mt++) {
        tile_tab0[n0++] = (k << 16) | mt;
        tile_tab1[n1++] = (k << 16) | mt;
      }
    *ntiles0 = n0; *ntiles1 = n1;
  }
  __syncthreads();
  if (q == 0) eoff[e] = offs[e];
  int idx = offs[e];
  for (int qq = 0; qq < q; qq++) idx += c4[e][qq];
  for (int i = lo; i < hiQ; i++)
    if (ti[i] == e) {
      tok_list[idx] = i / TOPK; slotg[i] = idx; wslot[idx] = topw[i]; idx++;
    }
}

// ------------------------------ combine ------------------------------------
__global__ __launch_bounds__(256) void combine_k(
    const unsigned short* __restrict__ shared_o, const unsigned short* __restrict__ out_e,
    const int* __restrict__ slotg, float* __restrict__ outp)
{
  int t = blockIdx.x, tid = threadIdx.x;
  int sl[TOPK];
#pragma unroll
  for (int j = 0; j < TOPK; j++) sl[j] = slotg[t * TOPK + j];
  long long d0 = (long long)t * DD + tid * 8;
  ushort8 sh = *(const ushort8*)(shared_o + d0);
  float a[8];
#pragma unroll
  for (int i = 0; i < 8; i++) a[i] = u2f(sh[i]);
#pragma unroll
  for (int j = 0; j < TOPK; j++) {
    ushort8 v = *(const ushort8*)(out_e + (long long)sl[j] * DD + tid * 8);
#pragma unroll
    for (int i = 0; i < 8; i++) a[i] += u2f(v[i]);
  }
#pragma unroll
  for (int i = 0; i < 8; i++) outp[d0 + i] = a[i];
}

// ---------------------------------------------------------------------------
extern "C" void kernel_launch(void* const* d_in, const int* in_sizes, int n_in,
                              void* d_out, int out_size, void* d_ws, size_t ws_size,
                              hipStream_t stream)
{
  (void)in_sizes; (void)n_in; (void)out_size; (void)ws_size;
  const int*   positions = (const int*)d_in[0];
  const float* hidden    = (const float*)d_in[1];
  const float* residual  = (const float*)d_in[2];
  const float* ln1_w     = (const float*)d_in[3];
  const float* ln2_w     = (const float*)d_in[4];
  const float* wqkv      = (const float*)d_in[5];
  const float* wo        = (const float*)d_in[6];
  const float* gate_w    = (const float*)d_in[7];
  const float* w1        = (const float*)d_in[8];
  const float* w2        = (const float*)d_in[9];
  const float* sw1       = (const float*)d_in[10];
  const float* sw2       = (const float*)d_in[11];

  float* outp      = (float*)d_out;
  float* resid_out = outp + (size_t)SS * DD;

  char* p = (char*)d_ws;
  auto alloc = [&](size_t b) { void* r = p; p += (b + 255) & ~(size_t)255; return r; };
  float*          x1       = (float*)alloc((size_t)SS * DD * 4);
  unsigned short* h1       = (unsigned short*)alloc((size_t)SS * DD * 2);
  unsigned short* qkv      = (unsigned short*)alloc((size_t)SS * NQKV * 2);
  unsigned short* qr       = (unsigned short*)alloc((size_t)SS * DD * 2);
  unsigned short* kr       = (unsigned short*)alloc((size_t)SS * DD * 2);
  unsigned short* ctx      = (unsigned short*)alloc((size_t)SS * DD * 2);
  unsigned short* attnout  = (unsigned short*)alloc((size_t)SS * DD * 2);
  unsigned short* h3       = (unsigned short*)alloc((size_t)SS * DD * 2);
  unsigned short* act_sh   = (unsigned short*)alloc((size_t)SS * ISHE * 2);
  unsigned short* shared_o = (unsigned short*)alloc((size_t)SS * DD * 2);
  unsigned short* act_e    = (unsigned short*)alloc((size_t)SS * TOPK * IEXP * 2);
  unsigned short* out_e    = (unsigned short*)alloc((size_t)SS * TOPK * DD * 2);
  unsigned short* wqkv_bf  = (unsigned short*)alloc((size_t)NQKV * DD * 2);
  unsigned short* wo_bf    = (unsigned short*)alloc((size_t)DD * DD * 2);
  unsigned short* sw1_bf   = (unsigned short*)alloc((size_t)2 * ISHE * DD * 2);
  unsigned short* sw2_bf   = (unsigned short*)alloc((size_t)DD * ISHE * 2);
  int*            topi     = (int*)alloc(SS * TOPK * 4);
  float*          topw     = (float*)alloc(SS * TOPK * 4);
  int*            slotg    = (int*)alloc(SS * TOPK * 4);
  int*            tok_list = (int*)alloc(SS * TOPK * 4);
  float*          wslot    = (float*)alloc(SS * TOPK * 4);
  int*            ecnt     = (int*)alloc(NEXP * 4);
  int*            eoff     = (int*)alloc(NEXP * 4);
  int*            tile_tab0= (int*)alloc(NT0 * 4);
  int*            tile_tab1= (int*)alloc(NT1 * 4);
  int*            ntiles0  = (int*)alloc(4);
  int*            ntiles1  = (int*)alloc(4);

  const long long CVT_ELEMS = (long long)NQKV * DD + (long long)DD * DD
                            + (long long)2 * ISHE * DD + (long long)DD * ISHE;
  const unsigned CVTB = (unsigned)(CVT_ELEMS / 2048);
  // fused: addnorm1 (blocks 0..SS-1) + weight conversion (blocks SS..)
  prep_k<<<SS + CVTB, 256, 0, stream>>>(hidden, residual, ln1_w, x1, h1,
                                        wqkv, wo, sw1, sw2,
                                        wqkv_bf, wo_bf, sw1_bf, sw2_bf);
  gemm_bb<<<dim3(NQKV/64, SS/64), 256, 0, stream>>>(h1, wqkv_bf, qkv, NQKV, DD, DD);
  rope_k<<<SS, 256, 0, stream>>>(positions, qkv, qr, kr);
  attn_k<<<dim3(NH, SS/32), 128, 0, stream>>>(qr, kr, qkv, ctx);
  gemm_bb<<<dim3(DD/64, SS/64), 256, 0, stream>>>(ctx, wo_bf, attnout, DD, DD, DD);
  an2gate_k<<<SS/8, 256, 0, stream>>>(attnout, x1, ln2_w, resid_out, h3,
                                      gate_w, topi, topw);
  route_k<<<1, 256, 0, stream>>>(topi, topw, ecnt, eoff, tok_list, slotg, wslot,
                                 tile_tab0, tile_tab1, ntiles0, ntiles1);
  moe_k<0><<<dim3(IEXP/64, NT0), 256, 0, stream>>>(
      h3, nullptr, nullptr, w1, sw1_bf, w2, sw2_bf, act_e, act_sh, nullptr, nullptr,
      ecnt, eoff, tok_list, wslot, tile_tab0, ntiles0);
  moe_k<1><<<dim3(DD/64, NT1), 256, 0, stream>>>(
      nullptr, act_e, act_sh, w1, sw1_bf, w2, sw2_bf, nullptr, nullptr, out_e, shared_o,
      ecnt, eoff, tok_list, wslot, tile_tab1, ntiles1);
  combine_k<<<SS, 256, 0, stream>>>(shared_o, out_e, slotg, outp);
  // ---- DIAGNOSTIC: 20 empty launches -> per-launch overhead --------------
  for (int i = 0; i < 20; i++) nop_k<<<1, 64, 0, stream>>>();
}

// Round 17
// 763.500 us; speedup vs baseline: 1.0360x; 1.0360x over previous
//
#include <hip/hip_runtime.h>
#include <hip/hip_bf16.h>

// ---------------------------------------------------------------------------
// DeepSeek decoder layer. f32 inputs/outputs; internal bf16 (+f32 residual).
// r17 = r16 clean (diagnostic nops removed). Final structure:
//   prep (addnorm1 + weight cvt) -> qkv GEMM -> rope -> flash attn ->
//   wo GEMM -> an2+gating -> route -> MoE0 (experts+shared, silu fused) ->
//   MoE1 (down, topk-scale fused) -> combine.
// MoE measured at ~85% of HBM pattern ceiling (3 engines tie); dense GEMMs
// at gll16-engine ceiling; per-launch overhead measured at ~1.4us.
// ---------------------------------------------------------------------------

typedef __attribute__((ext_vector_type(4))) float  f32x4;
typedef __attribute__((ext_vector_type(8))) short  short8;
typedef __attribute__((ext_vector_type(8))) unsigned short ushort8;

#define SS    512
#define DD    2048
#define NH    16
#define HDIM  128
#define NQKV  6144
#define NEXP  64
#define TOPK  6
#define IEXP  1408
#define ISHE  2816
#define NT0   128
#define NT1   120
#define ATT_SCALE 0.08838834764831845f

__device__ __forceinline__ float u2f(unsigned short u) {
  return __uint_as_float(((unsigned int)u) << 16);
}
__device__ __forceinline__ unsigned short f2u(float f) {
  __hip_bfloat16 h = __float2bfloat16(f);   // RNE
  return *reinterpret_cast<unsigned short*>(&h);
}
__device__ __forceinline__ ushort8 cvt8(f32x4 a, f32x4 b) {
  ushort8 r;
  r[0]=f2u(a[0]); r[1]=f2u(a[1]); r[2]=f2u(a[2]); r[3]=f2u(a[3]);
  r[4]=f2u(b[0]); r[5]=f2u(b[1]); r[6]=f2u(b[2]); r[7]=f2u(b[3]);
  return r;
}

typedef __attribute__((address_space(3))) unsigned int lds_uint;
typedef const __attribute__((address_space(1))) unsigned int ga_uint;
__device__ __forceinline__ void gll16(const void* g, void* l) {
  __builtin_amdgcn_global_load_lds((ga_uint*)g, (lds_uint*)l, 16, 0, 0);
}

// ------ prep: blocks [0,SS) = addnorm1; blocks [SS,..) = weight cvt ---------
__global__ __launch_bounds__(256) void prep_k(
    const float* __restrict__ hid, const float* __restrict__ res,
    const float* __restrict__ w, float* __restrict__ x1,
    unsigned short* __restrict__ h1,
    const float* __restrict__ wqkv, const float* __restrict__ wo,
    const float* __restrict__ sw1, const float* __restrict__ sw2,
    unsigned short* __restrict__ wqkv_bf, unsigned short* __restrict__ wo_bf,
    unsigned short* __restrict__ sw1_bf, unsigned short* __restrict__ sw2_bf)
{
  int b = blockIdx.x, tid = threadIdx.x;
  if (b < SS) {
    long long base = (long long)b * DD + tid * 8;
    float x[8]; float ss = 0.f;
#pragma unroll
    for (int i = 0; i < 8; i++) {
      x[i] = hid[base + i] + res[base + i];
      ss += x[i] * x[i]; x1[base + i] = x[i];
    }
#pragma unroll
    for (int o = 1; o < 64; o <<= 1) ss += __shfl_xor(ss, o);
    __shared__ float r4[4];
    if ((tid & 63) == 0) r4[tid >> 6] = ss;
    __syncthreads();
    ss = r4[0] + r4[1] + r4[2] + r4[3];
    float rr = rsqrtf(ss * (1.f / DD) + 1e-6f);
#pragma unroll
    for (int i = 0; i < 8; i++) h1[base + i] = f2u(x[i] * rr * w[tid * 8 + i]);
    return;
  }
  long long i = ((long long)(b - SS) * 256 + tid) * 8;
  const long long S1 = (long long)NQKV * DD;
  const long long S2 = S1 + (long long)DD * DD;
  const long long S3 = S2 + (long long)2 * ISHE * DD;
  const float* src; unsigned short* dst; long long j;
  if (i < S1)      { src = wqkv; dst = wqkv_bf; j = i; }
  else if (i < S2) { src = wo;   dst = wo_bf;   j = i - S1; }
  else if (i < S3) { src = sw1;  dst = sw1_bf;  j = i - S2; }
  else             { src = sw2;  dst = sw2_bf;  j = i - S3; }
  f32x4 a = *(const f32x4*)(src + j);
  f32x4 bb = *(const f32x4*)(src + j + 4);
  *(ushort8*)(dst + j) = cvt8(a, bb);
}

// ------ FUSED addnorm2 + gating: 64 blocks x 8 tokens; h3 parked in LDS -----
__global__ __launch_bounds__(256) void an2gate_k(
    const unsigned short* __restrict__ attn, const float* __restrict__ x1,
    const float* __restrict__ w, float* __restrict__ resid_out,
    unsigned short* __restrict__ h3, const float* __restrict__ gw,
    int* __restrict__ topi, float* __restrict__ topw)
{
  __shared__ unsigned short hs[8][DD];
  __shared__ float r4[4];
  __shared__ float p[8][NEXP];
  int b = blockIdx.x, tid = threadIdx.x;

  for (int tk = 0; tk < 8; tk++) {
    int t = b * 8 + tk;
    long long base = (long long)t * DD + tid * 8;
    ushort8 va = *(const ushort8*)(attn + base);
    float x[8]; float ss = 0.f;
#pragma unroll
    for (int i = 0; i < 8; i++) {
      x[i] = u2f(va[i]) + x1[base + i]; ss += x[i] * x[i];
      resid_out[base + i] = x[i];
    }
#pragma unroll
    for (int o = 1; o < 64; o <<= 1) ss += __shfl_xor(ss, o);
    if ((tid & 63) == 0) r4[tid >> 6] = ss;
    __syncthreads();
    ss = r4[0] + r4[1] + r4[2] + r4[3];
    float rr = rsqrtf(ss * (1.f / DD) + 1e-6f);
    ushort8 hv;
#pragma unroll
    for (int i = 0; i < 8; i++) hv[i] = f2u(x[i] * rr * w[tid * 8 + i]);
    *(ushort8*)&hs[tk][tid * 8] = hv;
    *(ushort8*)(h3 + base) = hv;
    __syncthreads();
  }

  int e = tid & 63, g = tid >> 6;
  const float* wr = gw + (long long)e * DD;
  const unsigned short* h0 = hs[g * 2];
  const unsigned short* h1r = hs[g * 2 + 1];
  float a0 = 0.f, a1 = 0.f;
  for (int k = 0; k < DD; k += 8) {
    f32x4 w0 = *(const f32x4*)(wr + k);
    f32x4 w1 = *(const f32x4*)(wr + k + 4);
    ushort8 x0 = *(const ushort8*)(h0 + k);
    ushort8 x1v = *(const ushort8*)(h1r + k);
    a0 += u2f(x0[0])*w0[0] + u2f(x0[1])*w0[1] + u2f(x0[2])*w0[2] + u2f(x0[3])*w0[3]
        + u2f(x0[4])*w1[0] + u2f(x0[5])*w1[1] + u2f(x0[6])*w1[2] + u2f(x0[7])*w1[3];
    a1 += u2f(x1v[0])*w0[0] + u2f(x1v[1])*w0[1] + u2f(x1v[2])*w0[2] + u2f(x1v[3])*w0[3]
        + u2f(x1v[4])*w1[0] + u2f(x1v[5])*w1[1] + u2f(x1v[6])*w1[2] + u2f(x1v[7])*w1[3];
  }
  p[g * 2][e] = a0; p[g * 2 + 1][e] = a1;
  __syncthreads();
  if (tid < 8) {
    int t = b * 8 + tid;
    float* pr = p[tid];
    float mx = -1e30f;
    for (int j = 0; j < NEXP; j++) mx = fmaxf(mx, pr[j]);
    float s = 0.f;
    for (int j = 0; j < NEXP; j++) { pr[j] = __expf(pr[j] - mx); s += pr[j]; }
    float invs = 1.f / s;
    for (int j = 0; j < NEXP; j++) pr[j] *= invs;
    for (int r = 0; r < TOPK; r++) {
      int bi = 0; float bv = -1.f;
      for (int j = 0; j < NEXP; j++) if (pr[j] > bv) { bv = pr[j]; bi = j; }
      topi[t * TOPK + r] = bi; topw[t * TOPK + r] = bv; pr[bi] = -2.f;
    }
  }
}

// ---------------------------------------------------------------------------
// Dense bf16 x bf16 GEMM via global_load_lds, double-buffered (r11 engine).
// ---------------------------------------------------------------------------
__global__ __launch_bounds__(256) void gemm_bb(
    const unsigned short* __restrict__ A, const unsigned short* __restrict__ W,
    unsigned short* __restrict__ C, int Nh, int K, int lda)
{
  __shared__ __align__(16) unsigned short As[2][64][64];
  __shared__ __align__(16) unsigned short Bs[2][64][64];

  int m0 = blockIdx.y * 64;
  int n0 = blockIdx.x * 64;
  int tid = threadIdx.x, lane = tid & 63, w = tid >> 6;

  const unsigned short* asrc[2];
  const unsigned short* bsrc[2];
#pragma unroll
  for (int i = 0; i < 2; i++) {
    int c = w + i * 4;
    int r = c * 8 + (lane >> 3);
    int col = ((lane & 7) ^ (lane >> 3)) << 3;
    asrc[i] = A + (long long)(m0 + r) * lda + col;
    bsrc[i] = W + (long long)(n0 + r) * K + col;
  }

  int wm = (w >> 1) * 32, wn = (w & 1) * 32;
  int l15 = lane & 15, hi = lane >> 4;
  int key = l15 & 7;

  f32x4 acc[2][2] = {};

#define BSTAGE(buf, k0)                                                  \
  do {                                                                   \
    gll16((const char*)asrc[0] + (k0) * 2, &As[buf][w * 8][0]);          \
    gll16((const char*)asrc[1] + (k0) * 2, &As[buf][(w + 4) * 8][0]);    \
    gll16((const char*)bsrc[0] + (k0) * 2, &Bs[buf][w * 8][0]);          \
    gll16((const char*)bsrc[1] + (k0) * 2, &Bs[buf][(w + 4) * 8][0]);    \
  } while (0)

  BSTAGE(0, 0);
  int buf = 0;
  for (int k0 = 0; k0 < K; k0 += 64, buf ^= 1) {
    __syncthreads();
    if (k0 + 64 < K) BSTAGE(buf ^ 1, k0 + 64);
#pragma unroll
    for (int kk = 0; kk < 2; kk++) {
      short8 fa[2], fb[2];
#pragma unroll
      for (int f = 0; f < 2; f++) {
        fa[f] = *(const short8*)&As[buf][wm + f * 16 + l15][(((kk << 2) + hi) ^ key) << 3];
        fb[f] = *(const short8*)&Bs[buf][wn + f * 16 + l15][(((kk << 2) + hi) ^ key) << 3];
      }
#pragma unroll
      for (int fm = 0; fm < 2; fm++)
#pragma unroll
        for (int fn = 0; fn < 2; fn++)
          acc[fm][fn] = __builtin_amdgcn_mfma_f32_16x16x32_bf16(fa[fm], fb[fn], acc[fm][fn], 0, 0, 0);
    }
  }
#undef BSTAGE

  int r0q = hi * 4;
#pragma unroll
  for (int fm = 0; fm < 2; fm++) {
#pragma unroll
    for (int j = 0; j < 4; j++) {
      int m = m0 + wm + fm * 16 + r0q + j;
      unsigned short* Cp = C + (long long)m * Nh + n0 + wn;
#pragma unroll
      for (int fn = 0; fn < 2; fn++)
        Cp[fn * 16 + l15] = f2u(acc[fm][fn][j]);
    }
  }
}

// ---------------------------------------------------------------------------
// MoE GEMM: experts (f32 W) + shared expert (bf16 W, e==NEXP).
// ---------------------------------------------------------------------------
template<int STAGE>
__global__ __launch_bounds__(256) void moe_k(
    const unsigned short* __restrict__ h3,
    const unsigned short* __restrict__ act_e_in, const unsigned short* __restrict__ act_sh_in,
    const float* __restrict__ w1, const unsigned short* __restrict__ sw1_bf,
    const float* __restrict__ w2, const unsigned short* __restrict__ sw2_bf,
    unsigned short* __restrict__ act_e_out, unsigned short* __restrict__ act_sh_out,
    unsigned short* __restrict__ out_e, unsigned short* __restrict__ shared_o,
    const int* __restrict__ e_cnt, const int* __restrict__ e_off,
    const int* __restrict__ tok_list, const float* __restrict__ wslot,
    const int* __restrict__ tile_tab, const int* __restrict__ ntiles)
{
  constexpr bool SILU = (STAGE == 0);
  __shared__ __align__(16) unsigned short As[64][72];
  __shared__ __align__(16) unsigned short Bg[64][72];
  __shared__ __align__(16) unsigned short Bu[SILU ? 64 : 1][72];

  int yr = blockIdx.y;
  int y;
  if (STAGE == 0) y = (yr < 16) ? yr : 16 + ((yr - 16) & 7) * 14 + ((yr - 16) >> 3);
  else            y = (yr < 8)  ? yr : 8  + ((yr - 8) & 7) * 14 + ((yr - 8) >> 3);
  if (y >= *ntiles) return;
  int tt = tile_tab[y];
  int e = tt >> 16;
  int half = (tt >> 8) & 1;
  int m0 = (tt & 255) * 64;
  bool sh = (e == NEXP);
  int cnt  = sh ? SS : e_cnt[e];
  int roff = sh ? 0 : e_off[e];
  int n0 = blockIdx.x * 64 + ((STAGE == 0 && sh) ? half * IEXP : 0);

  int Nh, K, lda;
  const float* Wb32 = nullptr;
  const unsigned short* Wb16 = nullptr;
  const unsigned short* Abase;
  unsigned short* Cb;
  if (STAGE == 0) {
    K = DD; lda = DD; Abase = h3;
    if (sh) { Nh = ISHE; Wb16 = sw1_bf; Cb = act_sh_out; }
    else    { Nh = IEXP; Wb32 = w1 + (long long)e * 2 * IEXP * DD; Cb = act_e_out; }
  } else {
    Nh = DD;
    if (sh) { K = ISHE; lda = ISHE; Abase = act_sh_in; Wb16 = sw2_bf; Cb = shared_o; }
    else    { K = IEXP; lda = IEXP; Abase = act_e_in;
              Wb32 = w2 + (long long)e * DD * IEXP; Cb = out_e; }
  }

  int tid = threadIdx.x;
  int sr  = tid >> 2;
  int sce = (tid & 3) * 16;

  int am = m0 + sr; if (am >= cnt) am = cnt - 1;
  int arow;
  if (STAGE == 0) arow = sh ? am : tok_list[roff + am];
  else            arow = sh ? am : roff + am;
  const unsigned short* ap = Abase + (long long)arow * lda + sce;
  const float*          gp32 = Wb32 ? (Wb32 + (long long)(n0 + sr) * K + sce) : nullptr;
  const float*          up32 = (Wb32 && SILU) ? (Wb32 + (long long)(Nh + n0 + sr) * K + sce) : nullptr;
  const unsigned short* gp16 = Wb16 ? (Wb16 + (long long)(n0 + sr) * K + sce) : nullptr;
  const unsigned short* up16 = (Wb16 && SILU) ? (Wb16 + (long long)(Nh + n0 + sr) * K + sce) : nullptr;

  int lane = tid & 63, wid = tid >> 6;
  int wm = (wid >> 1) * 32, wn = (wid & 1) * 32;
  int l15 = lane & 15, hi = lane >> 4;

  f32x4 acc[2][2] = {};
  f32x4 accU[2][2] = {};
  ushort8 raA0, raA1, raB0, raB1;
  f32x4 rgA[4], ruA[4], rgB[4], ruB[4];
  union BC { f32x4 f; ushort8 s; };

#define MLOAD(k, r0, r1, g, u)                                     \
  do {                                                             \
    r0 = *(const ushort8*)(ap + (k));                              \
    r1 = *(const ushort8*)(ap + (k) + 8);                          \
    if (sh) {                                                      \
      g[0] = *(const f32x4*)(gp16 + (k));                          \
      g[1] = *(const f32x4*)(gp16 + (k) + 8);                      \
      if (SILU) {                                                  \
        u[0] = *(const f32x4*)(up16 + (k));                        \
        u[1] = *(const f32x4*)(up16 + (k) + 8);                    \
      }                                                            \
    } else {                                                       \
      _Pragma("unroll")                                            \
      for (int i_ = 0; i_ < 4; i_++) g[i_] = *(const f32x4*)(gp32 + (k) + 4 * i_); \
      if (SILU) {                                                  \
        _Pragma("unroll")                                          \
        for (int i_ = 0; i_ < 4; i_++) u[i_] = *(const f32x4*)(up32 + (k) + 4 * i_); \
      }                                                            \
    }                                                              \
  } while (0)

#define MSTORE(r0, r1, g, u)                                       \
  do {                                                             \
    *(ushort8*)&As[sr][sce]     = r0;                              \
    *(ushort8*)&As[sr][sce + 8] = r1;                              \
    if (sh) {                                                      \
      BC b0, b1; b0.f = g[0]; b1.f = g[1];                         \
      *(ushort8*)&Bg[sr][sce]     = b0.s;                          \
      *(ushort8*)&Bg[sr][sce + 8] = b1.s;                          \
      if (SILU) {                                                  \
        BC c0, c1; c0.f = u[0]; c1.f = u[1];                       \
        *(ushort8*)&Bu[sr][sce]     = c0.s;                        \
        *(ushort8*)&Bu[sr][sce + 8] = c1.s;                        \
      }                                                            \
    } else {                                                       \
      *(ushort8*)&Bg[sr][sce]     = cvt8(g[0], g[1]);              \
      *(ushort8*)&Bg[sr][sce + 8] = cvt8(g[2], g[3]);              \
      if (SILU) {                                                  \
        *(ushort8*)&Bu[sr][sce]     = cvt8(u[0], u[1]);            \
        *(ushort8*)&Bu[sr][sce + 8] = cvt8(u[2], u[3]);            \
      }                                                            \
    }                                                              \
  } while (0)

#define MMFMA                                                      \
  do {                                                             \
    _Pragma("unroll")                                              \
    for (int kk = 0; kk < 2; kk++) {                               \
      int kc = kk * 32 + hi * 8;                                   \
      short8 fa[2], fg[2];                                         \
      _Pragma("unroll")                                            \
      for (int f = 0; f < 2; f++) {                                \
        fa[f] = *(const short8*)&As[wm + f * 16 + l15][kc];        \
        fg[f] = *(const short8*)&Bg[wn + f * 16 + l15][kc];        \
      }                                                            \
      _Pragma("unroll")                                            \
      for (int fm = 0; fm < 2; fm++)                               \
        _Pragma("unroll")                                          \
        for (int fn = 0; fn < 2; fn++)                             \
          acc[fm][fn] = __builtin_amdgcn_mfma_f32_16x16x32_bf16(fa[fm], fg[fn], acc[fm][fn], 0, 0, 0); \
      if (SILU) {                                                  \
        short8 fu[2];                                              \
        _Pragma("unroll")                                          \
        for (int f = 0; f < 2; f++) fu[f] = *(const short8*)&Bu[wn + f * 16 + l15][kc]; \
        _Pragma("unroll")                                          \
        for (int fm = 0; fm < 2; fm++)                             \
          _Pragma("unroll")                                        \
          for (int fn = 0; fn < 2; fn++)                           \
            accU[fm][fn] = __builtin_amdgcn_mfma_f32_16x16x32_bf16(fa[fm], fu[fn], accU[fm][fn], 0, 0, 0); \
      }                                                            \
    }                                                              \
  } while (0)

  MLOAD(0,  raA0, raA1, rgA, ruA);
  MLOAD(64, raB0, raB1, rgB, ruB);
  for (int k0 = 0; k0 < K; k0 += 128) {
    __syncthreads();
    MSTORE(raA0, raA1, rgA, ruA);
    __syncthreads();
    if (k0 + 128 < K) MLOAD(k0 + 128, raA0, raA1, rgA, ruA);
    MMFMA;
    __syncthreads();
    MSTORE(raB0, raB1, rgB, ruB);
    __syncthreads();
    if (k0 + 192 < K) MLOAD(k0 + 192, raB0, raB1, rgB, ruB);
    MMFMA;
  }
#undef MLOAD
#undef MSTORE
#undef MMFMA

  int r0q = hi * 4;
#pragma unroll
  for (int fm = 0; fm < 2; fm++) {
#pragma unroll
    for (int j = 0; j < 4; j++) {
      int m = m0 + wm + fm * 16 + r0q + j;
      if (m >= cnt) continue;
      long long crow = sh ? m : (roff + m);
      float scale = (STAGE == 1 && !sh) ? wslot[crow] : 1.f;
      unsigned short* Cp = Cb + crow * (long long)Nh + n0 + wn;
#pragma unroll
      for (int fn = 0; fn < 2; fn++) {
        float v;
        if (SILU) {
          float g = acc[fm][fn][j], u = accU[fm][fn][j];
          v = (g / (1.f + __expf(-g))) * u;
        } else v = acc[fm][fn][j];
        Cp[fn * 16 + l15] = f2u(v * scale);
      }
    }
  }
}

// ------------------------------ RoPE (neox) --------------------------------
__global__ __launch_bounds__(256) void rope_k(
    const int* __restrict__ pos, const unsigned short* __restrict__ qkv,
    unsigned short* __restrict__ qr, unsigned short* __restrict__ kr)
{
  int t = blockIdx.x, tid = threadIdx.x;
  __shared__ float cs[64], sn[64];
  if (tid < 64) {
    float inv = __expf(-((float)(2 * tid) / 128.f) * logf(10000.f));
    float ang = (float)pos[t] * inv;
    cs[tid] = cosf(ang); sn[tid] = sinf(ang);
  }
  __syncthreads();
  const unsigned short* row = qkv + (long long)t * NQKV;
  for (int idx = tid; idx < NH * 64; idx += 256) {
    int hh = idx >> 6, i = idx & 63;
    long long o = ((long long)hh * SS + t) * HDIM;
    float x1 = u2f(row[hh*128 + i]), x2 = u2f(row[hh*128 + i + 64]);
    qr[o + i]      = f2u(x1 * cs[i] - x2 * sn[i]);
    qr[o + i + 64] = f2u(x2 * cs[i] + x1 * sn[i]);
    float y1 = u2f(row[2048 + hh*128 + i]), y2 = u2f(row[2048 + hh*128 + i + 64]);
    kr[o + i]      = f2u(y1 * cs[i] - y2 * sn[i]);
    kr[o + i + 64] = f2u(y2 * cs[i] + y1 * sn[i]);
  }
}

// ------- MFMA flash attention, 32 q-rows / block, 2 waves, 256 blocks -------
__global__ __launch_bounds__(128) void attn_k(
    const unsigned short* __restrict__ qr, const unsigned short* __restrict__ kr,
    const unsigned short* __restrict__ qkv, unsigned short* __restrict__ ctx)
{
  int h = blockIdx.x, qt = blockIdx.y, q0 = qt * 32;
  int tid = threadIdx.x, lane = tid & 63, w = tid >> 6;
  int l15 = lane & 15, hi = lane >> 4;

  __shared__ unsigned short Vt[128][72];
  __shared__ unsigned short Pl[2][16][72];

  short8 qf[4];
  const unsigned short* Qb = qr + ((long long)h * SS + q0 + w * 16 + l15) * HDIM + hi * 8;
#pragma unroll
  for (int kf = 0; kf < 4; kf++) qf[kf] = *(const short8*)(Qb + kf * 32);

  f32x4 o[8] = {};
  float m_run[4] = {-1e30f, -1e30f, -1e30f, -1e30f};
  float l_run[4] = {};
  int myq = w * 16 + hi * 4;

  int T = (q0 + 31) >> 6;
  int qoff = q0 - 64 * T;
  for (int kt = 0; kt <= T; kt++) {
    int kbase = kt * 64;
    __syncthreads();
    {
      int r = lane, d0 = w * 64;
      const unsigned short* Vp = qkv + (long long)(kbase + r) * NQKV + 4096 + h * HDIM + d0;
#pragma unroll
      for (int c = 0; c < 8; c++) {
        ushort8 v = *(const ushort8*)(Vp + c * 8);
#pragma unroll
        for (int i = 0; i < 8; i++) Vt[d0 + c * 8 + i][r] = v[i];
      }
    }
    f32x4 s[4] = {};
    const unsigned short* Kb = kr + ((long long)h * SS + kbase) * HDIM + hi * 8;
#pragma unroll
    for (int nf = 0; nf < 4; nf++) {
      const unsigned short* Kp = Kb + (long long)(nf * 16 + l15) * HDIM;
#pragma unroll
      for (int kf = 0; kf < 4; kf++) {
        short8 kf8 = *(const short8*)(Kp + kf * 32);
        s[nf] = __builtin_amdgcn_mfma_f32_16x16x32_bf16(qf[kf], kf8, s[nf], 0, 0, 0);
      }
    }
    bool last = (kt == T);
#pragma unroll
    for (int nf = 0; nf < 4; nf++) {
      int keyl = nf * 16 + l15;
#pragma unroll
      for (int j = 0; j < 4; j++) {
        float sv = s[nf][j] * ATT_SCALE;
        if (last && keyl > qoff + myq + j) sv = -1e30f;
        s[nf][j] = sv;
      }
    }
    float corr[4], mnew[4];
#pragma unroll
    for (int j = 0; j < 4; j++) {
      float mv = fmaxf(fmaxf(s[0][j], s[1][j]), fmaxf(s[2][j], s[3][j]));
#pragma unroll
      for (int ox = 1; ox < 16; ox <<= 1) mv = fmaxf(mv, __shfl_xor(mv, ox));
      mnew[j] = fmaxf(m_run[j], mv);
      corr[j] = __expf(m_run[j] - mnew[j]);
      m_run[j] = mnew[j];
    }
#pragma unroll
    for (int nf8 = 0; nf8 < 8; nf8++)
#pragma unroll
      for (int j = 0; j < 4; j++) o[nf8][j] *= corr[j];
    float rs[4] = {};
#pragma unroll
    for (int nf = 0; nf < 4; nf++) {
#pragma unroll
      for (int j = 0; j < 4; j++) {
        float pv = __expf(s[nf][j] - mnew[j]);
        rs[j] += pv;
        Pl[w][hi * 4 + j][nf * 16 + l15] = f2u(pv);
      }
    }
#pragma unroll
    for (int j = 0; j < 4; j++) {
      float sv = rs[j];
#pragma unroll
      for (int ox = 1; ox < 16; ox <<= 1) sv += __shfl_xor(sv, ox);
      l_run[j] = l_run[j] * corr[j] + sv;
    }
    __syncthreads();
#pragma unroll
    for (int kf2 = 0; kf2 < 2; kf2++) {
      short8 pa = *(const short8*)&Pl[w][l15][kf2 * 32 + hi * 8];
#pragma unroll
      for (int nf8 = 0; nf8 < 8; nf8++) {
        short8 vb = *(const short8*)&Vt[nf8 * 16 + l15][kf2 * 32 + hi * 8];
        o[nf8] = __builtin_amdgcn_mfma_f32_16x16x32_bf16(pa, vb, o[nf8], 0, 0, 0);
      }
    }
  }
#pragma unroll
  for (int j = 0; j < 4; j++) {
    float inv = 1.f / l_run[j];
    long long t = q0 + myq + j;
    unsigned short* Cp = ctx + t * (long long)DD + h * HDIM;
#pragma unroll
    for (int nf8 = 0; nf8 < 8; nf8++)
      Cp[nf8 * 16 + l15] = f2u(o[nf8][j] * inv);
  }
}

// --------------- routing: quartered scans; builds both tile tables ----------
__global__ __launch_bounds__(256) void route_k(
    const int* __restrict__ topi, const float* __restrict__ topw,
    int* __restrict__ ecnt, int* __restrict__ eoff,
    int* __restrict__ tok_list, int* __restrict__ slotg,
    float* __restrict__ wslot, int* __restrict__ tile_tab0,
    int* __restrict__ tile_tab1, int* __restrict__ ntiles0,
    int* __restrict__ ntiles1)
{
  __shared__ int ti[SS * TOPK];
  __shared__ int c4[NEXP][4];
  __shared__ int ctot[NEXP];
  __shared__ int offs[NEXP + 1];
  int tid = threadIdx.x;
  for (int i = tid; i < SS * TOPK; i += 256) ti[i] = topi[i];
  __syncthreads();
  int e = tid >> 2, q = tid & 3;
  const int QW = SS * TOPK / 4;
  int lo = q * QW, hiQ = lo + QW;
  int n = 0;
  for (int i = lo; i < hiQ; i++) n += (ti[i] == e);
  c4[e][q] = n;
  __syncthreads();
  if (q == 0) {
    int s = c4[e][0] + c4[e][1] + c4[e][2] + c4[e][3];
    ctot[e] = s; ecnt[e] = s;
  }
  __syncthreads();
  if (tid == 0) {
    offs[0] = 0;
    for (int k = 0; k < NEXP; k++) offs[k + 1] = offs[k] + ctot[k];
    int n0 = 0, n1 = 0;
    for (int mt = 0; mt < SS / 64; mt++) {
      tile_tab0[n0++] = (NEXP << 16) | (0 << 8) | mt;
      tile_tab0[n0++] = (NEXP << 16) | (1 << 8) | mt;
      tile_tab1[n1++] = (NEXP << 16) | mt;
    }
    for (int k = 0; k < NEXP; k++)
      for (int mt = 0; mt * 64 < ctot[k]; mt++) {
        tile_tab0[n0++] = (k << 16) | mt;
        tile_tab1[n1++] = (k << 16) | mt;
      }
    *ntiles0 = n0; *ntiles1 = n1;
  }
  __syncthreads();
  if (q == 0) eoff[e] = offs[e];
  int idx = offs[e];
  for (int qq = 0; qq < q; qq++) idx += c4[e][qq];
  for (int i = lo; i < hiQ; i++)
    if (ti[i] == e) {
      tok_list[idx] = i / TOPK; slotg[i] = idx; wslot[idx] = topw[i]; idx++;
    }
}

// ------------------------------ combine ------------------------------------
__global__ __launch_bounds__(256) void combine_k(
    const unsigned short* __restrict__ shared_o, const unsigned short* __restrict__ out_e,
    const int* __restrict__ slotg, float* __restrict__ outp)
{
  int t = blockIdx.x, tid = threadIdx.x;
  int sl[TOPK];
#pragma unroll
  for (int j = 0; j < TOPK; j++) sl[j] = slotg[t * TOPK + j];
  long long d0 = (long long)t * DD + tid * 8;
  ushort8 sh = *(const ushort8*)(shared_o + d0);
  float a[8];
#pragma unroll
  for (int i = 0; i < 8; i++) a[i] = u2f(sh[i]);
#pragma unroll
  for (int j = 0; j < TOPK; j++) {
    ushort8 v = *(const ushort8*)(out_e + (long long)sl[j] * DD + tid * 8);
#pragma unroll
    for (int i = 0; i < 8; i++) a[i] += u2f(v[i]);
  }
#pragma unroll
  for (int i = 0; i < 8; i++) outp[d0 + i] = a[i];
}

// ---------------------------------------------------------------------------
extern "C" void kernel_launch(void* const* d_in, const int* in_sizes, int n_in,
                              void* d_out, int out_size, void* d_ws, size_t ws_size,
                              hipStream_t stream)
{
  (void)in_sizes; (void)n_in; (void)out_size; (void)ws_size;
  const int*   positions = (const int*)d_in[0];
  const float* hidden    = (const float*)d_in[1];
  const float* residual  = (const float*)d_in[2];
  const float* ln1_w     = (const float*)d_in[3];
  const float* ln2_w     = (const float*)d_in[4];
  const float* wqkv      = (const float*)d_in[5];
  const float* wo        = (const float*)d_in[6];
  const float* gate_w    = (const float*)d_in[7];
  const float* w1        = (const float*)d_in[8];
  const float* w2        = (const float*)d_in[9];
  const float* sw1       = (const float*)d_in[10];
  const float* sw2       = (const float*)d_in[11];

  float* outp      = (float*)d_out;
  float* resid_out = outp + (size_t)SS * DD;

  char* p = (char*)d_ws;
  auto alloc = [&](size_t b) { void* r = p; p += (b + 255) & ~(size_t)255; return r; };
  float*          x1       = (float*)alloc((size_t)SS * DD * 4);
  unsigned short* h1       = (unsigned short*)alloc((size_t)SS * DD * 2);
  unsigned short* qkv      = (unsigned short*)alloc((size_t)SS * NQKV * 2);
  unsigned short* qr       = (unsigned short*)alloc((size_t)SS * DD * 2);
  unsigned short* kr       = (unsigned short*)alloc((size_t)SS * DD * 2);
  unsigned short* ctx      = (unsigned short*)alloc((size_t)SS * DD * 2);
  unsigned short* attnout  = (unsigned short*)alloc((size_t)SS * DD * 2);
  unsigned short* h3       = (unsigned short*)alloc((size_t)SS * DD * 2);
  unsigned short* act_sh   = (unsigned short*)alloc((size_t)SS * ISHE * 2);
  unsigned short* shared_o = (unsigned short*)alloc((size_t)SS * DD * 2);
  unsigned short* act_e    = (unsigned short*)alloc((size_t)SS * TOPK * IEXP * 2);
  unsigned short* out_e    = (unsigned short*)alloc((size_t)SS * TOPK * DD * 2);
  unsigned short* wqkv_bf  = (unsigned short*)alloc((size_t)NQKV * DD * 2);
  unsigned short* wo_bf    = (unsigned short*)alloc((size_t)DD * DD * 2);
  unsigned short* sw1_bf   = (unsigned short*)alloc((size_t)2 * ISHE * DD * 2);
  unsigned short* sw2_bf   = (unsigned short*)alloc((size_t)DD * ISHE * 2);
  int*            topi     = (int*)alloc(SS * TOPK * 4);
  float*          topw     = (float*)alloc(SS * TOPK * 4);
  int*            slotg    = (int*)alloc(SS * TOPK * 4);
  int*            tok_list = (int*)alloc(SS * TOPK * 4);
  float*          wslot    = (float*)alloc(SS * TOPK * 4);
  int*            ecnt     = (int*)alloc(NEXP * 4);
  int*            eoff     = (int*)alloc(NEXP * 4);
  int*            tile_tab0= (int*)alloc(NT0 * 4);
  int*            tile_tab1= (int*)alloc(NT1 * 4);
  int*            ntiles0  = (int*)alloc(4);
  int*            ntiles1  = (int*)alloc(4);

  const long long CVT_ELEMS = (long long)NQKV * DD + (long long)DD * DD
                            + (long long)2 * ISHE * DD + (long long)DD * ISHE;
  const unsigned CVTB = (unsigned)(CVT_ELEMS / 2048);
  prep_k<<<SS + CVTB, 256, 0, stream>>>(hidden, residual, ln1_w, x1, h1,
                                        wqkv, wo, sw1, sw2,
                                        wqkv_bf, wo_bf, sw1_bf, sw2_bf);
  gemm_bb<<<dim3(NQKV/64, SS/64), 256, 0, stream>>>(h1, wqkv_bf, qkv, NQKV, DD, DD);
  rope_k<<<SS, 256, 0, stream>>>(positions, qkv, qr, kr);
  attn_k<<<dim3(NH, SS/32), 128, 0, stream>>>(qr, kr, qkv, ctx);
  gemm_bb<<<dim3(DD/64, SS/64), 256, 0, stream>>>(ctx, wo_bf, attnout, DD, DD, DD);
  an2gate_k<<<SS/8, 256, 0, stream>>>(attnout, x1, ln2_w, resid_out, h3,
                                      gate_w, topi, topw);
  route_k<<<1, 256, 0, stream>>>(topi, topw, ecnt, eoff, tok_list, slotg, wslot,
                                 tile_tab0, tile_tab1, ntiles0, ntiles1);
  moe_k<0><<<dim3(IEXP/64, NT0), 256, 0, stream>>>(
      h3, nullptr, nullptr, w1, sw1_bf, w2, sw2_bf, act_e, act_sh, nullptr, nullptr,
      ecnt, eoff, tok_list, wslot, tile_tab0, ntiles0);
  moe_k<1><<<dim3(DD/64, NT1), 256, 0, stream>>>(
      nullptr, act_e, act_sh, w1, sw1_bf, w2, sw2_bf, nullptr, nullptr, out_e, shared_o,
      ecnt, eoff, tok_list, wslot, tile_tab1, ntiles1);
  combine_k<<<SS, 256, 0, stream>>>(shared_o, out_e, slotg, outp);
}